// Round 12
// baseline (318.449 us; speedup 1.0000x reference)
//
#include <hip/hip_runtime.h>
#include <math.h>

// HydraAttention R16 — reductions folded into GEMM epilogues + occupancy.
//   1. gemm3 KV-job epilogue: colsq[b][n] (Sum K^2 over c) and vsum[b][c]
//      (Sum V over n) accumulated via shfl-reduce + atomicAdd from the f32
//      accumulators already in registers. Eliminates sumsqK (16MB re-read)
//      and the V-half of scale_sums (16MB read).
//   2. scale_sums -> scaleK (2048 blocks, K rows only, inline 1/sqrt(colsq)).
//   3. gemm_kv: 128x128 -> 64x64 tiles, grid 1024 = 4 blocks/CU (was 2),
//      conv-proven 8-slot swizzle staging (row stride 64 u16, 0-conflict).
//   4. transX + colsq/vsum zeroing folded into prep1. 10 -> 8 launches.
// conv_gemm untouched (R10 body; LDS-BW floor ~55us for this structure).

typedef unsigned short u16;
typedef __attribute__((ext_vector_type(8))) short short8;
typedef __attribute__((ext_vector_type(4))) float f32x4;
typedef __attribute__((ext_vector_type(4))) unsigned short us4v;

#define ASYNC16(g, l) __builtin_amdgcn_global_load_lds( \
    (const __attribute__((address_space(1))) unsigned int*)(g), \
    (__attribute__((address_space(3))) unsigned int*)(l), 16, 0, 0)

static __device__ __forceinline__ float b2f(u16 h) {
  unsigned int u = ((unsigned int)h) << 16;
  return __builtin_bit_cast(float, u);
}
static __device__ __forceinline__ u16 f2b(float f) {
  unsigned int u = __builtin_bit_cast(unsigned int, f);
  u += 0x7fffu + ((u >> 16) & 1u);
  return (u16)(u >> 16);
}

#define NB 1048576L

// ---------------- prep1: converts + kvbias + zero page + prep_T + transX + zeros ----------------
// 0..5631: weight converts; 5632: kvbias+zbuf; 5633..5888: prep_T;
// 5889..7936: transX; 7937..8064: zero colsq; 8065..8072: zero vsum.
__global__ __launch_bounds__(256) void prep1(
    const float* __restrict__ qw, const float* __restrict__ kw,
    const float* __restrict__ vw, const float* __restrict__ rw,
    const float* __restrict__ c1w, const float* __restrict__ c2w,
    const float* __restrict__ kb, const float* __restrict__ vb,
    const float* __restrict__ rb,
    u16* __restrict__ qw16, u16* __restrict__ kvw16, u16* __restrict__ rwT16,
    u16* __restrict__ wr1, u16* __restrict__ wr2,
    float* __restrict__ kvbias, float* __restrict__ zbuf, float* __restrict__ T,
    const float* __restrict__ x, u16* __restrict__ xT,
    float* __restrict__ colsq, float* __restrict__ vsum)
{
  __shared__ float Tl[64][65];
  int bb = blockIdx.x, t = threadIdx.x;
  if (bb >= 8065) {                       // zero vsum (2048 floats)
    int idx = (bb - 8065) * 256 + t;
    vsum[idx] = 0.f;
    return;
  }
  if (bb >= 7937) {                       // zero colsq (32768 floats)
    colsq[(bb - 7937) * 256 + t] = 0.f;
    return;
  }
  if (bb >= 5889) {                       // transX
    int lin = bb - 5889;
    int n0 = (lin & 63) * 64, c0 = ((lin >> 6) & 3) * 64, b = lin >> 8;
#pragma unroll
    for (int i = 0; i < 4; i++) {
      int c = (t >> 4) + i * 16, nn = (t & 15) * 4;
      float4 v = *(const float4*)&x[(long)b * NB + (long)(c0 + c) * 4096 + n0 + nn];
      Tl[c][nn] = v.x; Tl[c][nn + 1] = v.y; Tl[c][nn + 2] = v.z; Tl[c][nn + 3] = v.w;
    }
    __syncthreads();
#pragma unroll
    for (int i = 0; i < 4; i++) {
      int n = (t >> 4) + i * 16, cc = (t & 15) * 4;
      us4v o;
#pragma unroll
      for (int e = 0; e < 4; e++) o[e] = f2b(Tl[cc + e][n]);
      *(us4v*)&xT[(long)b * NB + (long)(n0 + n) * 256 + c0 + cc] = o;
    }
    return;
  }
  if (bb >= 5633) {                       // prep_T
    int m = bb - 5633, co = t;
    float r = rb[co];
    const float* p = c1w + (long)m * 2304 + co * 9;
    float lv[9];
#pragma unroll
    for (int d = 0; d < 9; d++) lv[d] = p[d] * r;
#pragma unroll
    for (int d = 0; d < 9; d++)
#pragma unroll
      for (int off = 32; off; off >>= 1) lv[d] += __shfl_down(lv[d], off, 64);
    __shared__ float red[4][9];
    int w = co >> 6, l = co & 63;
    if (l == 0)
#pragma unroll
      for (int d = 0; d < 9; d++) red[w][d] = lv[d];
    __syncthreads();
    if (co < 9) T[m * 9 + co] = red[0][co] + red[1][co] + red[2][co] + red[3][co];
    return;
  }
  if (bb == 5632) {
    if (t < 256) { kvbias[t] = kb[t]; kvbias[t + 256] = vb[t]; }
    if (t < 64) zbuf[t] = 0.f;
    return;
  }
  long g = (long)bb * 256 + t;
  if (g < 65536) {
    qw16[g] = f2b(qw[g]);
  } else if (g < 196608) {
    long e = g - 65536;
    kvw16[e] = f2b(e < 65536 ? kw[e] : vw[e - 65536]);
  } else if (g < 262144) {
    long e = g - 196608;
    int cv = e >> 8, co = e & 255;
    rwT16[e] = f2b(rw[co * 256 + cv]);
  } else if (g < 851968) {
    long e = g - 262144;
    int m = e / 2304, r = e - m * 2304;
    int d = r >> 8, c = r & 255;
    wr1[e] = f2b(c1w[m * 2304 + c * 9 + d]);
  } else {
    long e = g - 851968;
    int m = e / 2304, r = e - m * 2304;
    int d = r >> 8, c = r & 255;
    wr2[e] = f2b(c2w[m * 2304 + c * 9 + d]);
  }
}

// ---------------- gemm3 + corr: three K=256 GEMMs (BK=32, 5/CU) + corr filler ----------------
// lin<36:    w1p = wr1 @ rwT; lin<548: Qt = xT @ qw^T + qb;
// lin<1572:  KV = [kw|vw] @ xT + bias  (+ colsq/vsum atomics);
// lin>=1572: corr filler (4096 blocks).
__global__ __launch_bounds__(256) void gemm3(
    const u16* __restrict__ wr1, const u16* __restrict__ rwT16, u16* __restrict__ w1p,
    const u16* __restrict__ xT, const u16* __restrict__ qw16, u16* __restrict__ Qt,
    const u16* __restrict__ kvw16, u16* __restrict__ KV,
    const float* __restrict__ qb, const float* __restrict__ kvbias,
    const float* __restrict__ T, const float* __restrict__ c1b,
    float* __restrict__ corr,
    float* __restrict__ colsq, float* __restrict__ vsum)
{
  __shared__ __align__(16) u16 As[2][128 * 32];   // 8KB per buf
  __shared__ __align__(16) u16 Bs[2][128 * 32];   // total 32KB -> 5 blocks/CU
  int lin = blockIdx.x;
  if (lin >= 1572) {
    int e = (lin - 1572) * 256 + threadIdx.x;
    int m = e & 255, p = e >> 8;
    int y = p >> 6, xx = p & 63;
    float s = c1b[m];
#pragma unroll
    for (int d = 0; d < 9; d++) {
      int dy = d / 3 - 1, dx = d - (d / 3) * 3 - 1;
      if ((unsigned)(y + dy) < 64u && (unsigned)(xx + dx) < 64u) s += T[m * 9 + d];
    }
    corr[e] = s;
    return;
  }
  const u16 *A, *B;
  u16* out;
  const float *p1, *p2;
  long i0, j0, aoff, boff, ooff, sR;
  int job, bz = 0;
  if (lin < 36) {
    int bx = lin & 1, by = lin >> 1;
    A = wr1; B = rwT16; out = w1p;
    i0 = by * 128; j0 = bx * 128;
    aoff = 0; boff = 0; ooff = 0; sR = 256;
    p1 = nullptr; p2 = nullptr; job = 0;
  } else if (lin < 548) {
    int e = lin - 36;
    int bx = e & 1, by = (e >> 1) & 31, b = e >> 6;
    A = xT; B = qw16; out = Qt;
    i0 = by * 128; j0 = bx * 128;
    aoff = (long)b * NB; boff = 0; ooff = (long)b * NB; sR = 256;
    p1 = nullptr; p2 = qb; job = 1; bz = b;
  } else {
    int e = lin - 548;
    int bx = e & 31, by = (e >> 5) & 3, b = e >> 7;
    A = kvw16; B = xT; out = KV;
    i0 = by * 128; j0 = bx * 128;
    aoff = 0; boff = (long)b * NB; ooff = (long)b * 2 * NB; sR = 4096;
    p1 = kvbias; p2 = nullptr; job = 2; bz = b;
  }
  const u16* Ab = A + aoff + i0 * 256;
  const u16* Bb = B + boff + j0 * 256;
  int t = threadIdx.x, wave = t >> 6, lane = t & 63;
  int wi = (wave >> 1) * 64, wj = (wave & 1) * 64;
  int li = lane & 15, quad = lane >> 4;
  int qs = (lane & 3) ^ ((lane >> 3) & 3);   // stage source column (4-slot swizzle)
  int qx = quad ^ ((lane >> 1) & 3);         // read quad-slot
  int r0 = (wave * 128 + lane) >> 2;
  int r1 = (wave * 128 + 64 + lane) >> 2;
  f32x4 acc[4][4];
#pragma unroll
  for (int i = 0; i < 4; i++)
#pragma unroll
    for (int j = 0; j < 4; j++) acc[i][j] = (f32x4){0.f, 0.f, 0.f, 0.f};

  auto STAGE = [&](int kc, int buf) {
    int k0 = kc * 32;
    ASYNC16(Ab + (long)r0 * 256 + k0 + qs * 8, &As[buf][(wave * 128) * 8]);
    ASYNC16(Bb + (long)r0 * 256 + k0 + qs * 8, &Bs[buf][(wave * 128) * 8]);
    ASYNC16(Ab + (long)r1 * 256 + k0 + qs * 8, &As[buf][(wave * 128 + 64) * 8]);
    ASYNC16(Bb + (long)r1 * 256 + k0 + qs * 8, &Bs[buf][(wave * 128 + 64) * 8]);
  };

  int cur = 0;
  STAGE(0, 0);
#pragma unroll 1
  for (int kc = 0; kc < 8; kc++) {
    if (kc + 1 < 8) {
      STAGE(kc + 1, cur ^ 1);
      asm volatile("s_waitcnt vmcnt(4)" ::: "memory");   // stage kc landed
    } else {
      asm volatile("s_waitcnt vmcnt(0)" ::: "memory");
    }
    __builtin_amdgcn_s_barrier();
    const u16* as = &As[cur][0];
    const u16* bs = &Bs[cur][0];
    short8 af[4], bf[4];
#pragma unroll
    for (int s = 0; s < 4; s++) af[s] = *(const short8*)&as[(wi + s * 16 + li) * 32 + qx * 8];
#pragma unroll
    for (int s = 0; s < 4; s++) bf[s] = *(const short8*)&bs[(wj + s * 16 + li) * 32 + qx * 8];
#pragma unroll
    for (int si = 0; si < 4; si++)
#pragma unroll
      for (int sj = 0; sj < 4; sj++)
        acc[si][sj] = __builtin_amdgcn_mfma_f32_16x16x32_bf16(af[si], bf[sj], acc[si][sj], 0, 0, 0);
    __builtin_amdgcn_s_barrier();
    cur ^= 1;
  }

#pragma unroll
  for (int si = 0; si < 4; si++)
#pragma unroll
    for (int sj = 0; sj < 4; sj++) {
      long col = j0 + wj + sj * 16 + li;
#pragma unroll
      for (int r = 0; r < 4; r++) {
        long row = i0 + wi + si * 16 + quad * 4 + r;
        float v = acc[si][sj][r];
        if (p1) v += p1[row];
        if (p2) v += p2[col];
        out[ooff + row * sR + col] = f2b(v);
      }
    }

  if (job == 2) {
    if (i0 < 256) {
      // K rows: colsq[b][n] += sum over rows of v^2
#pragma unroll
      for (int sj = 0; sj < 4; sj++) {
        long col = j0 + wj + sj * 16 + li;
        float c2 = 0.f;
#pragma unroll
        for (int si = 0; si < 4; si++)
#pragma unroll
          for (int r = 0; r < 4; r++) {
            float v = acc[si][sj][r] + p1[i0 + wi + si * 16 + quad * 4 + r];
            c2 = fmaf(v, v, c2);
          }
        c2 += __shfl_xor(c2, 16, 64);
        c2 += __shfl_xor(c2, 32, 64);
        if (quad == 0) atomicAdd(&colsq[bz * 4096 + col], c2);
      }
    } else {
      // V rows: vsum[b][c] += sum over cols of v   (c = row - 256)
#pragma unroll
      for (int si = 0; si < 4; si++)
#pragma unroll
        for (int r = 0; r < 4; r++) {
          long row = i0 + wi + si * 16 + quad * 4 + r;
          float p = acc[si][0][r] + acc[si][1][r] + acc[si][2][r] + acc[si][3][r]
                    + 4.0f * p1[row];
#pragma unroll
          for (int m = 1; m < 16; m <<= 1) p += __shfl_xor(p, m, 64);
          if (li == 0) atomicAdd(&vsum[bz * 256 + (row - 256)], p);
        }
    }
  }
}

// ---------------- scaleK: K rows *= 1/sqrt(colsq); ksum[b][c] = row-sum ----------------
__global__ __launch_bounds__(256) void scaleK(
    u16* __restrict__ KV, const float* __restrict__ colsq, float* __restrict__ ksum)
{
  int z = blockIdx.x;                    // 2048
  int b = z >> 8, c = z & 255;
  u16* row = KV + (long)b * 2 * NB + (long)c * 4096;
  const float* cs = colsq + b * 4096;
  int t = threadIdx.x;
  float s = 0.f;
  short8 v0 = *(const short8*)&row[t * 16];
  short8 v1 = *(const short8*)&row[t * 16 + 8];
  short8 o0, o1;
#pragma unroll
  for (int e = 0; e < 8; e++) {
    float q0 = 1.0f / sqrtf(cs[t * 16 + e]);
    float q1 = 1.0f / sqrtf(cs[t * 16 + 8 + e]);
    float a = b2f((u16)v0[e]) * q0;
    float bb = b2f((u16)v1[e]) * q1;
    s += a + bb;
    o0[e] = (short)f2b(a); o1[e] = (short)f2b(bb);
  }
  *(short8*)&row[t * 16] = o0;
  *(short8*)&row[t * 16 + 8] = o1;
#pragma unroll
  for (int off = 32; off; off >>= 1) s += __shfl_down(s, off, 64);
  __shared__ float red[4];
  if ((t & 63) == 0) red[t >> 6] = s;
  __syncthreads();
  if (t == 0) ksum[b * 256 + c] = red[0] + red[1] + red[2] + red[3];
}

// ---------------- kv split-n GEMM: 64x64 tile, BK=64, 1024 blocks = 4/CU ----------------
// grid (4,4,64): bx = cv tile (64), by = ck tile (64), z = b + 8*sp
__global__ __launch_bounds__(256) void gemm_kv(
    const u16* __restrict__ KV, float* __restrict__ part)
{
  __shared__ __align__(16) u16 As[2][64 * 64];    // 8KB per buf
  __shared__ __align__(16) u16 Bs[2][64 * 64];    // total 32KB
  int z = blockIdx.z;
  int b = z & 7, sp = z >> 3;
  long i0 = (long)blockIdx.y * 64;    // ck
  long j0 = (long)blockIdx.x * 64;    // cv
  const u16* Ab = KV + (long)b * 2 * NB + i0 * 4096;        // K rows
  const u16* Bb = KV + (long)b * 2 * NB + NB + j0 * 4096;   // V rows
  int t = threadIdx.x, wave = t >> 6, lane = t & 63;
  int wm = (wave >> 1) * 32, wn = (wave & 1) * 32;
  int li = lane & 15, quad = lane >> 4;
  int qs8 = (lane & 7) ^ ((lane >> 3) & 7);
  f32x4 acc[2][2];
#pragma unroll
  for (int i = 0; i < 2; i++)
#pragma unroll
    for (int j = 0; j < 2; j++) acc[i][j] = (f32x4){0.f, 0.f, 0.f, 0.f};

  // 4 ASYNC16/thread/stage (2 j-rounds x {A,B}); conv-proven 8-slot swizzle
  auto STAGE = [&](int kc, int buf) {
    long k0 = (long)sp * 512 + kc * 64 + qs8 * 8;
#pragma unroll
    for (int j = 0; j < 2; j++) {
      int row = (wave * 2 + j) * 8 + (lane >> 3);
      ASYNC16(Ab + (long)row * 4096 + k0, &As[buf][(wave * 2 + j) * 512]);
      ASYNC16(Bb + (long)row * 4096 + k0, &Bs[buf][(wave * 2 + j) * 512]);
    }
  };

  int cur = 0;
  STAGE(0, 0);
#pragma unroll 1
  for (int kc = 0; kc < 8; kc++) {
    if (kc + 1 < 8) {
      STAGE(kc + 1, cur ^ 1);
      asm volatile("s_waitcnt vmcnt(4)" ::: "memory");
    } else {
      asm volatile("s_waitcnt vmcnt(0)" ::: "memory");
    }
    __builtin_amdgcn_s_barrier();
    const u16* as = &As[cur][0];
    const u16* bs = &Bs[cur][0];
#pragma unroll
    for (int kk = 0; kk < 2; kk++) {
      short8 af[2], bf[2];
      int slot = (((kk << 2) | quad) ^ (lane & 7)) * 8;
#pragma unroll
      for (int s = 0; s < 2; s++) af[s] = *(const short8*)&as[(wm + s * 16 + li) * 64 + slot];
#pragma unroll
      for (int s = 0; s < 2; s++) bf[s] = *(const short8*)&bs[(wn + s * 16 + li) * 64 + slot];
#pragma unroll
      for (int si = 0; si < 2; si++)
#pragma unroll
        for (int sj = 0; sj < 2; sj++)
          acc[si][sj] = __builtin_amdgcn_mfma_f32_16x16x32_bf16(af[si], bf[sj], acc[si][sj], 0, 0, 0);
    }
    __builtin_amdgcn_s_barrier();
    cur ^= 1;
  }

  float* outp = part + ((long)sp * 8 + b) * 65536;
#pragma unroll
  for (int si = 0; si < 2; si++)
#pragma unroll
    for (int sj = 0; sj < 2; sj++) {
      long col = j0 + wn + sj * 16 + li;   // cv
#pragma unroll
      for (int r = 0; r < 4; r++) {
        long row = i0 + wm + si * 16 + quad * 4 + r;  // ck
        outp[col * 256 + row] = acc[si][sj][r];
      }
    }
}

// ---------------- fused: reduce_kv (blocks 0..2047) + qden (blocks 2048..10239) ----------------
__global__ __launch_bounds__(256) void redkv_qden(
    const float* __restrict__ part, u16* __restrict__ kvT,
    const u16* __restrict__ Qt, const float* __restrict__ ksum,
    float* __restrict__ rq, float* __restrict__ den)
{
  int bb = blockIdx.x;
  if (bb < 2048) {
    int g = bb * 256 + threadIdx.x;  // 524288
    float s = 0.f;
#pragma unroll
    for (int sp = 0; sp < 8; sp++) s += part[(long)sp * 524288 + g];
    kvT[g] = f2b(s);
    return;
  }
  int row = (bb - 2048) * 4 + (threadIdx.x >> 6);
  int lane = threadIdx.x & 63;
  int b = row >> 12;
  us4v v = *(const us4v*)(Qt + (long)row * 256 + lane * 4);
  float4 ks = *(const float4*)&ksum[b * 256 + lane * 4];
  float f0 = b2f(v[0]), f1 = b2f(v[1]), f2 = b2f(v[2]), f3 = b2f(v[3]);
  float s = f0 * f0 + f1 * f1 + f2 * f2 + f3 * f3;
  float s2 = f0 * ks.x + f1 * ks.y + f2 * ks.z + f3 * ks.w;
#pragma unroll
  for (int m = 32; m; m >>= 1) {
    s += __shfl_xor(s, m, 64);
    s2 += __shfl_xor(s2, m, 64);
  }
  if (lane == 0) {
    float r = 1.0f / sqrtf(s);
    rq[row] = r;
    den[row] = 1.0f / (4096.0f + s2 * r + 1e-6f);
  }
}

// ---------------- gemm_wv: wv = (Qt @ kvT * rq + vsum) * den  (BK=32, 5/CU) ----------------
__global__ __launch_bounds__(256) void gemm_wv(
    const u16* __restrict__ Qt, const u16* __restrict__ kvT, u16* __restrict__ wvT,
    const float* __restrict__ vsum, const float* __restrict__ den,
    const float* __restrict__ rq)
{
  __shared__ __align__(16) u16 As[2][128 * 32];
  __shared__ __align__(16) u16 Bs[2][128 * 32];
  int lin = blockIdx.x;
  int bx = lin & 1, by = (lin >> 1) & 31, b = lin >> 6;
  long i0 = (long)by * 128;   // n
  long j0 = (long)bx * 128;   // cv
  const u16* Ab = Qt + (long)b * NB + i0 * 256;
  const u16* Bb = kvT + (long)b * 65536 + j0 * 256;
  int t = threadIdx.x, wave = t >> 6, lane = t & 63;
  int wi = (wave >> 1) * 64, wj = (wave & 1) * 64;
  int li = lane & 15, quad = lane >> 4;
  int qs = (lane & 3) ^ ((lane >> 3) & 3);
  int qx = quad ^ ((lane >> 1) & 3);
  int r0 = (wave * 128 + lane) >> 2;
  int r1 = (wave * 128 + 64 + lane) >> 2;
  f32x4 acc[4][4];
#pragma unroll
  for (int i = 0; i < 4; i++)
#pragma unroll
    for (int j = 0; j < 4; j++) acc[i][j] = (f32x4){0.f, 0.f, 0.f, 0.f};

  auto STAGE = [&](int kc, int buf) {
    int k0 = kc * 32;
    ASYNC16(Ab + (long)r0 * 256 + k0 + qs * 8, &As[buf][(wave * 128) * 8]);
    ASYNC16(Bb + (long)r0 * 256 + k0 + qs * 8, &Bs[buf][(wave * 128) * 8]);
    ASYNC16(Ab + (long)r1 * 256 + k0 + qs * 8, &As[buf][(wave * 128 + 64) * 8]);
    ASYNC16(Bb + (long)r1 * 256 + k0 + qs * 8, &Bs[buf][(wave * 128 + 64) * 8]);
  };

  int cur = 0;
  STAGE(0, 0);
#pragma unroll 1
  for (int kc = 0; kc < 8; kc++) {
    if (kc + 1 < 8) {
      STAGE(kc + 1, cur ^ 1);
      asm volatile("s_waitcnt vmcnt(4)" ::: "memory");
    } else {
      asm volatile("s_waitcnt vmcnt(0)" ::: "memory");
    }
    __builtin_amdgcn_s_barrier();
    const u16* as = &As[cur][0];
    const u16* bs = &Bs[cur][0];
    short8 af[4], bf[4];
#pragma unroll
    for (int s = 0; s < 4; s++) af[s] = *(const short8*)&as[(wi + s * 16 + li) * 32 + qx * 8];
#pragma unroll
    for (int s = 0; s < 4; s++) bf[s] = *(const short8*)&bs[(wj + s * 16 + li) * 32 + qx * 8];
#pragma unroll
    for (int si = 0; si < 4; si++)
#pragma unroll
      for (int sj = 0; sj < 4; sj++)
        acc[si][sj] = __builtin_amdgcn_mfma_f32_16x16x32_bf16(af[si], bf[sj], acc[si][sj], 0, 0, 0);
    __builtin_amdgcn_s_barrier();
    cur ^= 1;
  }

#pragma unroll
  for (int si = 0; si < 4; si++)
#pragma unroll
    for (int sj = 0; sj < 4; sj++) {
      long col = j0 + wj + sj * 16 + li;
#pragma unroll
      for (int r = 0; r < 4; r++) {
        long row = i0 + wi + si * 16 + quad * 4 + r;
        float v = (acc[si][sj][r] * rq[b * 4096 + row] + vsum[b * 256 + col])
                  * den[b * 4096 + row];
        wvT[(long)b * NB + row * 256 + col] = f2b(v);
      }
    }
}

// ---------------- conv3x3 implicit GEMM: 256x128 tile, BK=64 (R10-proven body) ----------------
__global__ __launch_bounds__(512, 2) void conv_gemm(
    const u16* __restrict__ inT, const u16* __restrict__ wr,
    const float* __restrict__ cb, const float* __restrict__ xres,
    const float* __restrict__ zbuf,
    u16* __restrict__ out16, float* __restrict__ out32, int mode)
{
  __shared__ __align__(16) u16 S[2 * 24576];  // per buf: A @0 (16384 u16), B @16384 (8192 u16)

  int lin = blockIdx.x;            // 256 blocks
  int b   = lin & 7;               // XCD == batch under round-robin dispatch
  int n0  = (lin >> 3) * 128;      // n tile = 2 image rows; full M per block

  int t = threadIdx.x, wave = t >> 6, lane = t & 63;
  int wm = (wave >> 1) * 64, wn = (wave & 1) * 64;
  int li = lane & 15, quad = lane >> 4;
  int qs8 = (lane & 7) ^ ((lane >> 3) & 7);   // stage source slot (8-slot swizzle)
  const u16* inb = inT + (long)b * NB;

  int rr = wave * 8 + (lane >> 3);
  const u16* Ap0 = wr + (long)(rr)       * 2304 + qs8 * 8;
  const u16* Ap1 = wr + (long)(rr + 64)  * 2304 + qs8 * 8;
  const u16* Ap2 = wr + (long)(rr + 128) * 2304 + qs8 * 8;
  const u16* Ap3 = wr + (long)(rr + 192) * 2304 + qs8 * 8;
  const u16* Bp0 = inb + (long)(n0 + rr) * 256 + qs8 * 8;
  const u16* Bp1 = inb + (long)(n0 + 64 + rr) * 256 + qs8 * 8;
  const u16* zp  = (const u16*)zbuf + qs8 * 8;
  int yb0 = n0 >> 6, xb = rr;

  f32x4 acc[4][4];
#pragma unroll
  for (int i = 0; i < 4; i++)
#pragma unroll
    for (int j = 0; j < 4; j++) acc[i][j] = (f32x4){0.f, 0.f, 0.f, 0.f};

  auto STAGE = [&](int ks, int buf) {
    int d = ks >> 2;                          // tap (4 steps per tap)
    int dy = d / 3 - 1, dx = d - (d / 3) * 3 - 1;
    long shA = (long)ks * 64;                 // = d*256 + (ks&3)*64
    long shB = (long)(dy * 64 + dx) * 256 + (ks & 3) * 64;
    u16* base = &S[buf * 24576];
    ASYNC16(Ap0 + shA, base + wave * 512);
    ASYNC16(Ap1 + shA, base + 4096 + wave * 512);
    ASYNC16(Ap2 + shA, base + 8192 + wave * 512);
    ASYNC16(Ap3 + shA, base + 12288 + wave * 512);
    bool v0 = ((unsigned)(yb0 + dy) < 64u) && ((unsigned)(xb + dx) < 64u);
    bool v1 = ((unsigned)(yb0 + 1 + dy) < 64u) && ((unsigned)(xb + dx) < 64u);
    ASYNC16(v0 ? Bp0 + shB : zp, base + 16384 + wave * 512);
    ASYNC16(v1 ? Bp1 + shB : zp, base + 20480 + wave * 512);
  };

  int cur = 0;
  STAGE(0, 0);
#pragma unroll 1
  for (int ks = 0; ks < 36; ks++) {
    if (ks + 1 < 36) {
      STAGE(ks + 1, cur ^ 1);
      asm volatile("s_waitcnt vmcnt(6)" ::: "memory");   // stage ks landed
    } else {
      asm volatile("s_waitcnt vmcnt(0)" ::: "memory");
    }
    __builtin_amdgcn_s_barrier();
    const u16* as = &S[cur * 24576];
    const u16* bs = as + 16384;
#pragma unroll
    for (int kk = 0; kk < 2; kk++) {
      short8 af[4], bf[4];
      int slot = (((kk << 2) | quad) ^ (lane & 7)) * 8;
#pragma unroll
      for (int s = 0; s < 4; s++) af[s] = *(const short8*)&as[(wm + s * 16 + li) * 64 + slot];
#pragma unroll
      for (int s = 0; s < 4; s++) bf[s] = *(const short8*)&bs[(wn + s * 16 + li) * 64 + slot];
#pragma unroll
      for (int si = 0; si < 4; si++)
#pragma unroll
        for (int sj = 0; sj < 4; sj++)
          acc[si][sj] = __builtin_amdgcn_mfma_f32_16x16x32_bf16(af[si], bf[sj], acc[si][sj], 0, 0, 0);
    }
    __builtin_amdgcn_s_barrier();                        // all reads of cur done
    cur ^= 1;
  }

#pragma unroll
  for (int si = 0; si < 4; si++)
#pragma unroll
    for (int sj = 0; sj < 4; sj++) {
      int n = n0 + wn + sj * 16 + li;                // n
      int m0 = wm + si * 16 + quad * 4;              // m base (multiple of 4)
      if (mode == 0) {
        f32x4 c4 = *(const f32x4*)&cb[(long)n * 256 + m0];
        us4v o;
#pragma unroll
        for (int r = 0; r < 4; r++) o[r] = f2b(acc[si][sj][r] + c4[r]);
        *(us4v*)&out16[(long)b * NB + (long)n * 256 + m0] = o;
      } else {
#pragma unroll
        for (int r = 0; r < 4; r++) {
          int m = m0 + r;
          float v = acc[si][sj][r] + cb[m];
          long a = (long)b * NB + (long)m * 4096 + n;
          float xv = xres[a];
          out32[a] = fmaf(v, xv, xv);
        }
      }
    }
}

// ---------------- host ----------------
extern "C" void kernel_launch(void* const* d_in, const int* in_sizes, int n_in,
                              void* d_out, int out_size, void* d_ws, size_t ws_size,
                              hipStream_t stream)
{
  const float* x   = (const float*)d_in[0];
  const float* qw  = (const float*)d_in[1];
  const float* qb  = (const float*)d_in[2];
  const float* kw  = (const float*)d_in[3];
  const float* kb  = (const float*)d_in[4];
  const float* vw  = (const float*)d_in[5];
  const float* vb  = (const float*)d_in[6];
  const float* rw  = (const float*)d_in[7];
  const float* rb  = (const float*)d_in[8];
  const float* c1w = (const float*)d_in[9];
  const float* c1b = (const float*)d_in[10];
  const float* c2w = (const float*)d_in[11];
  const float* c2b = (const float*)d_in[12];

  // ws layout (u16 units)
  u16* U     = (u16*)d_ws;
  u16* xT16  = U;                     // 8388608 ; later wvT16
  u16* Qt16  = U + 8388608;           // 8388608 ; later h1T16
  u16* KV16  = U + 16777216;          // 16777216 (K rows 0-255, V rows 256-511 per b)
  u16* wr2   = U + 33554432;          // 589824
  u16* kvT16 = U + 34144256;          // 524288
  float* Fws = (float*)(U + 34668544);
  float* ksum = Fws;                  // 2048
  float* vsum = Fws + 2048;           // 2048 (atomically accumulated in gemm3)
  float* zbuf = Fws + 4096;           // 64 (zero page for conv OOB loads)

  // d_out scratch (all dead before conv2 writes d_out; conv2 reads NOTHING here)
  char* ob = (char*)d_out;
  float* kvpart = (float*)(ob + 0);           // 16777216 B
  float* den    = (float*)(ob + 16777216);    // 131072
  float* colsq  = (float*)(ob + 16908288);    // 131072 (atomically accumulated)
  float* corr   = (float*)(ob + 17039360);    // 4194304  (layout [n][m])
  u16*   w1p16  = (u16*)(ob + 21233664);      // 1179648
  u16*   wr1    = (u16*)(ob + 22413312);      // 1179648
  float* T      = (float*)(ob + 23592960);    // 36864
  u16*   rwT16  = (u16*)(ob + 23629824);      // 131072
  u16*   qw16   = (u16*)(ob + 23760896);      // 131072
  u16*   kvw16  = (u16*)(ob + 23891968);      // 262144
  float* kvbias = (float*)(ob + 24154112);    // 2048
  float* rq     = (float*)(ob + 24158208);    // 131072 (qden output, dead by conv1)
  float* outF   = (float*)d_out;

  u16* wvT16 = xT16;
  u16* h1T16 = Qt16;

  dim3 blk(256);

  // converts(5632) + bias(1) + prep_T(256) + transX(2048) + zero colsq(128) + zero vsum(8)
  prep1<<<8073, blk, 0, stream>>>(qw, kw, vw, rw, c1w, c2w, kb, vb, rb,
                                  qw16, kvw16, rwT16, wr1, wr2, kvbias, zbuf, T,
                                  x, xT16, colsq, vsum);

  // fused: w1p (36) + Qt (512) + KV (1024, + colsq/vsum atomics) + corr (4096)
  gemm3<<<5668, blk, 0, stream>>>(wr1, rwT16, w1p16, xT16, qw16, Qt16,
                                  kvw16, KV16, qb, kvbias, T, c1b, corr,
                                  colsq, vsum);

  scaleK<<<2048, blk, 0, stream>>>(KV16, colsq, ksum);

  gemm_kv<<<dim3(4, 4, 64), blk, 0, stream>>>(KV16, kvpart);
  redkv_qden<<<10240, blk, 0, stream>>>(kvpart, kvT16, Qt16, ksum, rq, den);

  // wvT[b][n][cv] = (Qt @ kvT * rq + vsum) * den
  gemm_wv<<<512, blk, 0, stream>>>(Qt16, kvT16, wvT16, vsum, den, rq);

  conv_gemm<<<256, 512, 0, stream>>>(wvT16, w1p16, corr, nullptr, zbuf,
                                     h1T16, nullptr, 0);
  conv_gemm<<<256, 512, 0, stream>>>(h1T16, wr2, c2b, x, zbuf,
                                     nullptr, outF, 1);
}

// Round 13
// 307.996 us; speedup vs baseline: 1.0339x; 1.0339x over previous
//
#include <hip/hip_runtime.h>
#include <math.h>

// HydraAttention R17 — surgical revert of R16's atomic epilogue (it cost +11us
// on gemm3: device-scope atomicAdd + shfl tail on a latency-bound kernel,
// exceeding the ~8us saved by dropping sumsqK/scale_sums-V). gemm3 back to the
// R15-proven epilogue-free body; sumsqK + scale_sums restored verbatim.
// KEPT from R16 (independent, verified): gemm_kv 64x64 @ 4 blocks/CU, and
// transX folded into prep1. conv_gemm untouched (R10 body, ~56us LDS floor).

typedef unsigned short u16;
typedef __attribute__((ext_vector_type(8))) short short8;
typedef __attribute__((ext_vector_type(4))) float f32x4;
typedef __attribute__((ext_vector_type(4))) unsigned short us4v;

#define ASYNC16(g, l) __builtin_amdgcn_global_load_lds( \
    (const __attribute__((address_space(1))) unsigned int*)(g), \
    (__attribute__((address_space(3))) unsigned int*)(l), 16, 0, 0)

static __device__ __forceinline__ float b2f(u16 h) {
  unsigned int u = ((unsigned int)h) << 16;
  return __builtin_bit_cast(float, u);
}
static __device__ __forceinline__ u16 f2b(float f) {
  unsigned int u = __builtin_bit_cast(unsigned int, f);
  u += 0x7fffu + ((u >> 16) & 1u);
  return (u16)(u >> 16);
}

#define NB 1048576L

// ---------------- prep1: converts + kvbias + zero page + prep_T + transX ----------------
// 0..5631: weight converts; 5632: kvbias+zbuf; 5633..5888: prep_T; 5889..7936: transX.
__global__ __launch_bounds__(256) void prep1(
    const float* __restrict__ qw, const float* __restrict__ kw,
    const float* __restrict__ vw, const float* __restrict__ rw,
    const float* __restrict__ c1w, const float* __restrict__ c2w,
    const float* __restrict__ kb, const float* __restrict__ vb,
    const float* __restrict__ rb,
    u16* __restrict__ qw16, u16* __restrict__ kvw16, u16* __restrict__ rwT16,
    u16* __restrict__ wr1, u16* __restrict__ wr2,
    float* __restrict__ kvbias, float* __restrict__ zbuf, float* __restrict__ T,
    const float* __restrict__ x, u16* __restrict__ xT)
{
  __shared__ float Tl[64][65];
  int bb = blockIdx.x, t = threadIdx.x;
  if (bb >= 5889) {                       // transX
    int lin = bb - 5889;
    int n0 = (lin & 63) * 64, c0 = ((lin >> 6) & 3) * 64, b = lin >> 8;
#pragma unroll
    for (int i = 0; i < 4; i++) {
      int c = (t >> 4) + i * 16, nn = (t & 15) * 4;
      float4 v = *(const float4*)&x[(long)b * NB + (long)(c0 + c) * 4096 + n0 + nn];
      Tl[c][nn] = v.x; Tl[c][nn + 1] = v.y; Tl[c][nn + 2] = v.z; Tl[c][nn + 3] = v.w;
    }
    __syncthreads();
#pragma unroll
    for (int i = 0; i < 4; i++) {
      int n = (t >> 4) + i * 16, cc = (t & 15) * 4;
      us4v o;
#pragma unroll
      for (int e = 0; e < 4; e++) o[e] = f2b(Tl[cc + e][n]);
      *(us4v*)&xT[(long)b * NB + (long)(n0 + n) * 256 + c0 + cc] = o;
    }
    return;
  }
  if (bb >= 5633) {                       // prep_T
    int m = bb - 5633, co = t;
    float r = rb[co];
    const float* p = c1w + (long)m * 2304 + co * 9;
    float lv[9];
#pragma unroll
    for (int d = 0; d < 9; d++) lv[d] = p[d] * r;
#pragma unroll
    for (int d = 0; d < 9; d++)
#pragma unroll
      for (int off = 32; off; off >>= 1) lv[d] += __shfl_down(lv[d], off, 64);
    __shared__ float red[4][9];
    int w = co >> 6, l = co & 63;
    if (l == 0)
#pragma unroll
      for (int d = 0; d < 9; d++) red[w][d] = lv[d];
    __syncthreads();
    if (co < 9) T[m * 9 + co] = red[0][co] + red[1][co] + red[2][co] + red[3][co];
    return;
  }
  if (bb == 5632) {
    if (t < 256) { kvbias[t] = kb[t]; kvbias[t + 256] = vb[t]; }
    if (t < 64) zbuf[t] = 0.f;
    return;
  }
  long g = (long)bb * 256 + t;
  if (g < 65536) {
    qw16[g] = f2b(qw[g]);
  } else if (g < 196608) {
    long e = g - 65536;
    kvw16[e] = f2b(e < 65536 ? kw[e] : vw[e - 65536]);
  } else if (g < 262144) {
    long e = g - 196608;
    int cv = e >> 8, co = e & 255;
    rwT16[e] = f2b(rw[co * 256 + cv]);
  } else if (g < 851968) {
    long e = g - 262144;
    int m = e / 2304, r = e - m * 2304;
    int d = r >> 8, c = r & 255;
    wr1[e] = f2b(c1w[m * 2304 + c * 9 + d]);
  } else {
    long e = g - 851968;
    int m = e / 2304, r = e - m * 2304;
    int d = r >> 8, c = r & 255;
    wr2[e] = f2b(c2w[m * 2304 + c * 9 + d]);
  }
}

// ---------------- gemm3 + corr: three K=256 GEMMs (BK=32, 5/CU) + corr filler ----------------
// lin<36:    w1p [2304x256] = wr1 @ rwT            (36 blocks)
// lin<548:   Qt[b][n][ck]   = xT @ qw^T + qb       (512 blocks)
// lin<1572:  KV[b][cq][n]   = [kw|vw] @ xT + bias  (1024 blocks)
// lin>=1572: corr[p][m] = c1b[m] + sum_{valid taps} T[m][d]  (4096 blocks)
__global__ __launch_bounds__(256) void gemm3(
    const u16* __restrict__ wr1, const u16* __restrict__ rwT16, u16* __restrict__ w1p,
    const u16* __restrict__ xT, const u16* __restrict__ qw16, u16* __restrict__ Qt,
    const u16* __restrict__ kvw16, u16* __restrict__ KV,
    const float* __restrict__ qb, const float* __restrict__ kvbias,
    const float* __restrict__ T, const float* __restrict__ c1b,
    float* __restrict__ corr)
{
  __shared__ __align__(16) u16 As[2][128 * 32];   // 8KB per buf
  __shared__ __align__(16) u16 Bs[2][128 * 32];   // total 32KB -> 5 blocks/CU
  int lin = blockIdx.x;
  if (lin >= 1572) {
    int e = (lin - 1572) * 256 + threadIdx.x;
    int m = e & 255, p = e >> 8;
    int y = p >> 6, xx = p & 63;
    float s = c1b[m];
#pragma unroll
    for (int d = 0; d < 9; d++) {
      int dy = d / 3 - 1, dx = d - (d / 3) * 3 - 1;
      if ((unsigned)(y + dy) < 64u && (unsigned)(xx + dx) < 64u) s += T[m * 9 + d];
    }
    corr[e] = s;
    return;
  }
  const u16 *A, *B;
  u16* out;
  const float *p1, *p2;
  long i0, j0, aoff, boff, ooff, sR;
  if (lin < 36) {
    int bx = lin & 1, by = lin >> 1;
    A = wr1; B = rwT16; out = w1p;
    i0 = by * 128; j0 = bx * 128;
    aoff = 0; boff = 0; ooff = 0; sR = 256;
    p1 = nullptr; p2 = nullptr;
  } else if (lin < 548) {
    int e = lin - 36;
    int bx = e & 1, by = (e >> 1) & 31, b = e >> 6;
    A = xT; B = qw16; out = Qt;
    i0 = by * 128; j0 = bx * 128;
    aoff = (long)b * NB; boff = 0; ooff = (long)b * NB; sR = 256;
    p1 = nullptr; p2 = qb;
  } else {
    int e = lin - 548;
    int bx = e & 31, by = (e >> 5) & 3, b = e >> 7;
    A = kvw16; B = xT; out = KV;
    i0 = by * 128; j0 = bx * 128;
    aoff = 0; boff = (long)b * NB; ooff = (long)b * 2 * NB; sR = 4096;
    p1 = kvbias; p2 = nullptr;
  }
  const u16* Ab = A + aoff + i0 * 256;
  const u16* Bb = B + boff + j0 * 256;
  int t = threadIdx.x, wave = t >> 6, lane = t & 63;
  int wi = (wave >> 1) * 64, wj = (wave & 1) * 64;
  int li = lane & 15, quad = lane >> 4;
  int qs = (lane & 3) ^ ((lane >> 3) & 3);   // stage source column (4-slot swizzle)
  int qx = quad ^ ((lane >> 1) & 3);         // read quad-slot
  int r0 = (wave * 128 + lane) >> 2;
  int r1 = (wave * 128 + 64 + lane) >> 2;
  f32x4 acc[4][4];
#pragma unroll
  for (int i = 0; i < 4; i++)
#pragma unroll
    for (int j = 0; j < 4; j++) acc[i][j] = (f32x4){0.f, 0.f, 0.f, 0.f};

  auto STAGE = [&](int kc, int buf) {
    int k0 = kc * 32;
    ASYNC16(Ab + (long)r0 * 256 + k0 + qs * 8, &As[buf][(wave * 128) * 8]);
    ASYNC16(Bb + (long)r0 * 256 + k0 + qs * 8, &Bs[buf][(wave * 128) * 8]);
    ASYNC16(Ab + (long)r1 * 256 + k0 + qs * 8, &As[buf][(wave * 128 + 64) * 8]);
    ASYNC16(Bb + (long)r1 * 256 + k0 + qs * 8, &Bs[buf][(wave * 128 + 64) * 8]);
  };

  int cur = 0;
  STAGE(0, 0);
#pragma unroll 1
  for (int kc = 0; kc < 8; kc++) {
    if (kc + 1 < 8) {
      STAGE(kc + 1, cur ^ 1);
      asm volatile("s_waitcnt vmcnt(4)" ::: "memory");   // stage kc landed
    } else {
      asm volatile("s_waitcnt vmcnt(0)" ::: "memory");
    }
    __builtin_amdgcn_s_barrier();
    const u16* as = &As[cur][0];
    const u16* bs = &Bs[cur][0];
    short8 af[4], bf[4];
#pragma unroll
    for (int s = 0; s < 4; s++) af[s] = *(const short8*)&as[(wi + s * 16 + li) * 32 + qx * 8];
#pragma unroll
    for (int s = 0; s < 4; s++) bf[s] = *(const short8*)&bs[(wj + s * 16 + li) * 32 + qx * 8];
#pragma unroll
    for (int si = 0; si < 4; si++)
#pragma unroll
      for (int sj = 0; sj < 4; sj++)
        acc[si][sj] = __builtin_amdgcn_mfma_f32_16x16x32_bf16(af[si], bf[sj], acc[si][sj], 0, 0, 0);
    __builtin_amdgcn_s_barrier();
    cur ^= 1;
  }

#pragma unroll
  for (int si = 0; si < 4; si++)
#pragma unroll
    for (int sj = 0; sj < 4; sj++) {
      long col = j0 + wj + sj * 16 + li;
#pragma unroll
      for (int r = 0; r < 4; r++) {
        long row = i0 + wi + si * 16 + quad * 4 + r;
        float v = acc[si][sj][r];
        if (p1) v += p1[row];
        if (p2) v += p2[col];
        out[ooff + row * sR + col] = f2b(v);
      }
    }
}

// ---------------- K column sumsq -> rsqK[b][n] (512 blocks = 2/CU) ----------------
__global__ __launch_bounds__(256) void sumsqK(
    const u16* __restrict__ KV, float* __restrict__ rsqK)
{
  __shared__ float red[16][68];
  int b = blockIdx.x >> 6, nc = blockIdx.x & 63;
  int n0 = nc * 64;
  int t = threadIdx.x;
  int nn = (t & 15) * 4, cg = t >> 4;
  const u16* base = KV + (long)b * 2 * NB;
  float s0 = 0.f, s1 = 0.f, s2 = 0.f, s3 = 0.f;
  for (int st = 0; st < 16; st++) {
    int c = cg + st * 16;
    us4v v = *(const us4v*)(base + (long)c * 4096 + n0 + nn);
    float a = b2f(v[0]), bb = b2f(v[1]), cc = b2f(v[2]), dd = b2f(v[3]);
    s0 = fmaf(a, a, s0); s1 = fmaf(bb, bb, s1);
    s2 = fmaf(cc, cc, s2); s3 = fmaf(dd, dd, s3);
  }
  red[cg][nn] = s0; red[cg][nn + 1] = s1; red[cg][nn + 2] = s2; red[cg][nn + 3] = s3;
  __syncthreads();
  if (t < 64) {
    float s = 0.f;
#pragma unroll
    for (int g = 0; g < 16; g++) s += red[g][t];
    rsqK[b * 4096 + n0 + t] = 1.0f / sqrtf(s);
  }
}

// ---------------- scale K rows by rsqK + ksum; V rows -> vsum ----------------
__global__ __launch_bounds__(256) void scale_sums(
    u16* __restrict__ KV, const float* __restrict__ rsqK,
    float* __restrict__ ksum, float* __restrict__ vsum)
{
  int z = blockIdx.x;
  int isV = z >> 11, rem = z & 2047, b = rem >> 8, c = rem & 255;
  u16* row = KV + (long)b * 2 * NB + (long)isV * NB + (long)c * 4096;
  const float* rq = rsqK + b * 4096;
  int t = threadIdx.x;
  float s = 0.f;
  short8 v0 = *(const short8*)&row[t * 16];
  short8 v1 = *(const short8*)&row[t * 16 + 8];
  if (!isV) {
    short8 o0, o1;
#pragma unroll
    for (int e = 0; e < 8; e++) {
      float a = b2f((u16)v0[e]) * rq[t * 16 + e];
      float bb = b2f((u16)v1[e]) * rq[t * 16 + 8 + e];
      s += a + bb;
      o0[e] = (short)f2b(a); o1[e] = (short)f2b(bb);
    }
    *(short8*)&row[t * 16] = o0;
    *(short8*)&row[t * 16 + 8] = o1;
  } else {
#pragma unroll
    for (int e = 0; e < 8; e++) s += b2f((u16)v0[e]) + b2f((u16)v1[e]);
  }
#pragma unroll
  for (int off = 32; off; off >>= 1) s += __shfl_down(s, off, 64);
  __shared__ float red[4];
  if ((t & 63) == 0) red[t >> 6] = s;
  __syncthreads();
  if (t == 0)
    (isV ? vsum : ksum)[b * 256 + c] = red[0] + red[1] + red[2] + red[3];
}

// ---------------- kv split-n GEMM: 64x64 tile, BK=64, 1024 blocks = 4/CU ----------------
// grid (4,4,64): bx = cv tile (64), by = ck tile (64), z = b + 8*sp
__global__ __launch_bounds__(256) void gemm_kv(
    const u16* __restrict__ KV, float* __restrict__ part)
{
  __shared__ __align__(16) u16 As[2][64 * 64];    // 8KB per buf
  __shared__ __align__(16) u16 Bs[2][64 * 64];    // total 32KB
  int z = blockIdx.z;
  int b = z & 7, sp = z >> 3;
  long i0 = (long)blockIdx.y * 64;    // ck
  long j0 = (long)blockIdx.x * 64;    // cv
  const u16* Ab = KV + (long)b * 2 * NB + i0 * 4096;        // K rows
  const u16* Bb = KV + (long)b * 2 * NB + NB + j0 * 4096;   // V rows
  int t = threadIdx.x, wave = t >> 6, lane = t & 63;
  int wm = (wave >> 1) * 32, wn = (wave & 1) * 32;
  int li = lane & 15, quad = lane >> 4;
  int qs8 = (lane & 7) ^ ((lane >> 3) & 7);
  f32x4 acc[2][2];
#pragma unroll
  for (int i = 0; i < 2; i++)
#pragma unroll
    for (int j = 0; j < 2; j++) acc[i][j] = (f32x4){0.f, 0.f, 0.f, 0.f};

  // 4 ASYNC16/thread/stage (2 j-rounds x {A,B}); conv-proven 8-slot swizzle
  auto STAGE = [&](int kc, int buf) {
    long k0 = (long)sp * 512 + kc * 64 + qs8 * 8;
#pragma unroll
    for (int j = 0; j < 2; j++) {
      int row = (wave * 2 + j) * 8 + (lane >> 3);
      ASYNC16(Ab + (long)row * 4096 + k0, &As[buf][(wave * 2 + j) * 512]);
      ASYNC16(Bb + (long)row * 4096 + k0, &Bs[buf][(wave * 2 + j) * 512]);
    }
  };

  int cur = 0;
  STAGE(0, 0);
#pragma unroll 1
  for (int kc = 0; kc < 8; kc++) {
    if (kc + 1 < 8) {
      STAGE(kc + 1, cur ^ 1);
      asm volatile("s_waitcnt vmcnt(4)" ::: "memory");
    } else {
      asm volatile("s_waitcnt vmcnt(0)" ::: "memory");
    }
    __builtin_amdgcn_s_barrier();
    const u16* as = &As[cur][0];
    const u16* bs = &Bs[cur][0];
#pragma unroll
    for (int kk = 0; kk < 2; kk++) {
      short8 af[2], bf[2];
      int slot = (((kk << 2) | quad) ^ (lane & 7)) * 8;
#pragma unroll
      for (int s = 0; s < 2; s++) af[s] = *(const short8*)&as[(wm + s * 16 + li) * 64 + slot];
#pragma unroll
      for (int s = 0; s < 2; s++) bf[s] = *(const short8*)&bs[(wn + s * 16 + li) * 64 + slot];
#pragma unroll
      for (int si = 0; si < 2; si++)
#pragma unroll
        for (int sj = 0; sj < 2; sj++)
          acc[si][sj] = __builtin_amdgcn_mfma_f32_16x16x32_bf16(af[si], bf[sj], acc[si][sj], 0, 0, 0);
    }
    __builtin_amdgcn_s_barrier();
    cur ^= 1;
  }

  float* outp = part + ((long)sp * 8 + b) * 65536;
#pragma unroll
  for (int si = 0; si < 2; si++)
#pragma unroll
    for (int sj = 0; sj < 2; sj++) {
      long col = j0 + wn + sj * 16 + li;   // cv
#pragma unroll
      for (int r = 0; r < 4; r++) {
        long row = i0 + wm + si * 16 + quad * 4 + r;  // ck
        outp[col * 256 + row] = acc[si][sj][r];
      }
    }
}

// ---------------- fused: reduce_kv (blocks 0..2047) + qden (blocks 2048..10239) ----------------
__global__ __launch_bounds__(256) void redkv_qden(
    const float* __restrict__ part, u16* __restrict__ kvT,
    const u16* __restrict__ Qt, const float* __restrict__ ksum,
    float* __restrict__ rq, float* __restrict__ den)
{
  int bb = blockIdx.x;
  if (bb < 2048) {
    int g = bb * 256 + threadIdx.x;  // 524288
    float s = 0.f;
#pragma unroll
    for (int sp = 0; sp < 8; sp++) s += part[(long)sp * 524288 + g];
    kvT[g] = f2b(s);
    return;
  }
  int row = (bb - 2048) * 4 + (threadIdx.x >> 6);
  int lane = threadIdx.x & 63;
  int b = row >> 12;
  us4v v = *(const us4v*)(Qt + (long)row * 256 + lane * 4);
  float4 ks = *(const float4*)&ksum[b * 256 + lane * 4];
  float f0 = b2f(v[0]), f1 = b2f(v[1]), f2 = b2f(v[2]), f3 = b2f(v[3]);
  float s = f0 * f0 + f1 * f1 + f2 * f2 + f3 * f3;
  float s2 = f0 * ks.x + f1 * ks.y + f2 * ks.z + f3 * ks.w;
#pragma unroll
  for (int m = 32; m; m >>= 1) {
    s += __shfl_xor(s, m, 64);
    s2 += __shfl_xor(s2, m, 64);
  }
  if (lane == 0) {
    float r = 1.0f / sqrtf(s);
    rq[row] = r;
    den[row] = 1.0f / (4096.0f + s2 * r + 1e-6f);
  }
}

// ---------------- gemm_wv: wv = (Qt @ kvT * rq + vsum) * den  (BK=32, 5/CU) ----------------
__global__ __launch_bounds__(256) void gemm_wv(
    const u16* __restrict__ Qt, const u16* __restrict__ kvT, u16* __restrict__ wvT,
    const float* __restrict__ vsum, const float* __restrict__ den,
    const float* __restrict__ rq)
{
  __shared__ __align__(16) u16 As[2][128 * 32];
  __shared__ __align__(16) u16 Bs[2][128 * 32];
  int lin = blockIdx.x;
  int bx = lin & 1, by = (lin >> 1) & 31, b = lin >> 6;
  long i0 = (long)by * 128;   // n
  long j0 = (long)bx * 128;   // cv
  const u16* Ab = Qt + (long)b * NB + i0 * 256;
  const u16* Bb = kvT + (long)b * 65536 + j0 * 256;
  int t = threadIdx.x, wave = t >> 6, lane = t & 63;
  int wi = (wave >> 1) * 64, wj = (wave & 1) * 64;
  int li = lane & 15, quad = lane >> 4;
  int qs = (lane & 3) ^ ((lane >> 3) & 3);
  int qx = quad ^ ((lane >> 1) & 3);
  int r0 = (wave * 128 + lane) >> 2;
  int r1 = (wave * 128 + 64 + lane) >> 2;
  f32x4 acc[4][4];
#pragma unroll
  for (int i = 0; i < 4; i++)
#pragma unroll
    for (int j = 0; j < 4; j++) acc[i][j] = (f32x4){0.f, 0.f, 0.f, 0.f};

  auto STAGE = [&](int kc, int buf) {
    int k0 = kc * 32;
    ASYNC16(Ab + (long)r0 * 256 + k0 + qs * 8, &As[buf][(wave * 128) * 8]);
    ASYNC16(Bb + (long)r0 * 256 + k0 + qs * 8, &Bs[buf][(wave * 128) * 8]);
    ASYNC16(Ab + (long)r1 * 256 + k0 + qs * 8, &As[buf][(wave * 128 + 64) * 8]);
    ASYNC16(Bb + (long)r1 * 256 + k0 + qs * 8, &Bs[buf][(wave * 128 + 64) * 8]);
  };

  int cur = 0;
  STAGE(0, 0);
#pragma unroll 1
  for (int kc = 0; kc < 8; kc++) {
    if (kc + 1 < 8) {
      STAGE(kc + 1, cur ^ 1);
      asm volatile("s_waitcnt vmcnt(4)" ::: "memory");
    } else {
      asm volatile("s_waitcnt vmcnt(0)" ::: "memory");
    }
    __builtin_amdgcn_s_barrier();
    const u16* as = &As[cur][0];
    const u16* bs = &Bs[cur][0];
    short8 af[4], bf[4];
#pragma unroll
    for (int s = 0; s < 4; s++) af[s] = *(const short8*)&as[(wi + s * 16 + li) * 32 + qx * 8];
#pragma unroll
    for (int s = 0; s < 4; s++) bf[s] = *(const short8*)&bs[(wj + s * 16 + li) * 32 + qx * 8];
#pragma unroll
    for (int si = 0; si < 4; si++)
#pragma unroll
      for (int sj = 0; sj < 4; sj++)
        acc[si][sj] = __builtin_amdgcn_mfma_f32_16x16x32_bf16(af[si], bf[sj], acc[si][sj], 0, 0, 0);
    __builtin_amdgcn_s_barrier();
    cur ^= 1;
  }

#pragma unroll
  for (int si = 0; si < 4; si++)
#pragma unroll
    for (int sj = 0; sj < 4; sj++) {
      long col = j0 + wj + sj * 16 + li;
#pragma unroll
      for (int r = 0; r < 4; r++) {
        long row = i0 + wi + si * 16 + quad * 4 + r;
        float v = (acc[si][sj][r] * rq[b * 4096 + row] + vsum[b * 256 + col])
                  * den[b * 4096 + row];
        wvT[(long)b * NB + row * 256 + col] = f2b(v);
      }
    }
}

// ---------------- conv3x3 implicit GEMM: 256x128 tile, BK=64 (R10-proven body) ----------------
__global__ __launch_bounds__(512, 2) void conv_gemm(
    const u16* __restrict__ inT, const u16* __restrict__ wr,
    const float* __restrict__ cb, const float* __restrict__ xres,
    const float* __restrict__ zbuf,
    u16* __restrict__ out16, float* __restrict__ out32, int mode)
{
  __shared__ __align__(16) u16 S[2 * 24576];  // per buf: A @0 (16384 u16), B @16384 (8192 u16)

  int lin = blockIdx.x;            // 256 blocks
  int b   = lin & 7;               // XCD == batch under round-robin dispatch
  int n0  = (lin >> 3) * 128;      // n tile = 2 image rows; full M per block

  int t = threadIdx.x, wave = t >> 6, lane = t & 63;
  int wm = (wave >> 1) * 64, wn = (wave & 1) * 64;
  int li = lane & 15, quad = lane >> 4;
  int qs8 = (lane & 7) ^ ((lane >> 3) & 7);   // stage source slot (8-slot swizzle)
  const u16* inb = inT + (long)b * NB;

  int rr = wave * 8 + (lane >> 3);
  const u16* Ap0 = wr + (long)(rr)       * 2304 + qs8 * 8;
  const u16* Ap1 = wr + (long)(rr + 64)  * 2304 + qs8 * 8;
  const u16* Ap2 = wr + (long)(rr + 128) * 2304 + qs8 * 8;
  const u16* Ap3 = wr + (long)(rr + 192) * 2304 + qs8 * 8;
  const u16* Bp0 = inb + (long)(n0 + rr) * 256 + qs8 * 8;
  const u16* Bp1 = inb + (long)(n0 + 64 + rr) * 256 + qs8 * 8;
  const u16* zp  = (const u16*)zbuf + qs8 * 8;
  int yb0 = n0 >> 6, xb = rr;

  f32x4 acc[4][4];
#pragma unroll
  for (int i = 0; i < 4; i++)
#pragma unroll
    for (int j = 0; j < 4; j++) acc[i][j] = (f32x4){0.f, 0.f, 0.f, 0.f};

  auto STAGE = [&](int ks, int buf) {
    int d = ks >> 2;                          // tap (4 steps per tap)
    int dy = d / 3 - 1, dx = d - (d / 3) * 3 - 1;
    long shA = (long)ks * 64;                 // = d*256 + (ks&3)*64
    long shB = (long)(dy * 64 + dx) * 256 + (ks & 3) * 64;
    u16* base = &S[buf * 24576];
    ASYNC16(Ap0 + shA, base + wave * 512);
    ASYNC16(Ap1 + shA, base + 4096 + wave * 512);
    ASYNC16(Ap2 + shA, base + 8192 + wave * 512);
    ASYNC16(Ap3 + shA, base + 12288 + wave * 512);
    bool v0 = ((unsigned)(yb0 + dy) < 64u) && ((unsigned)(xb + dx) < 64u);
    bool v1 = ((unsigned)(yb0 + 1 + dy) < 64u) && ((unsigned)(xb + dx) < 64u);
    ASYNC16(v0 ? Bp0 + shB : zp, base + 16384 + wave * 512);
    ASYNC16(v1 ? Bp1 + shB : zp, base + 20480 + wave * 512);
  };

  int cur = 0;
  STAGE(0, 0);
#pragma unroll 1
  for (int ks = 0; ks < 36; ks++) {
    if (ks + 1 < 36) {
      STAGE(ks + 1, cur ^ 1);
      asm volatile("s_waitcnt vmcnt(6)" ::: "memory");   // stage ks landed
    } else {
      asm volatile("s_waitcnt vmcnt(0)" ::: "memory");
    }
    __builtin_amdgcn_s_barrier();
    const u16* as = &S[cur * 24576];
    const u16* bs = as + 16384;
#pragma unroll
    for (int kk = 0; kk < 2; kk++) {
      short8 af[4], bf[4];
      int slot = (((kk << 2) | quad) ^ (lane & 7)) * 8;
#pragma unroll
      for (int s = 0; s < 4; s++) af[s] = *(const short8*)&as[(wm + s * 16 + li) * 64 + slot];
#pragma unroll
      for (int s = 0; s < 4; s++) bf[s] = *(const short8*)&bs[(wn + s * 16 + li) * 64 + slot];
#pragma unroll
      for (int si = 0; si < 4; si++)
#pragma unroll
        for (int sj = 0; sj < 4; sj++)
          acc[si][sj] = __builtin_amdgcn_mfma_f32_16x16x32_bf16(af[si], bf[sj], acc[si][sj], 0, 0, 0);
    }
    __builtin_amdgcn_s_barrier();                        // all reads of cur done
    cur ^= 1;
  }

#pragma unroll
  for (int si = 0; si < 4; si++)
#pragma unroll
    for (int sj = 0; sj < 4; sj++) {
      int n = n0 + wn + sj * 16 + li;                // n
      int m0 = wm + si * 16 + quad * 4;              // m base (multiple of 4)
      if (mode == 0) {
        f32x4 c4 = *(const f32x4*)&cb[(long)n * 256 + m0];
        us4v o;
#pragma unroll
        for (int r = 0; r < 4; r++) o[r] = f2b(acc[si][sj][r] + c4[r]);
        *(us4v*)&out16[(long)b * NB + (long)n * 256 + m0] = o;
      } else {
#pragma unroll
        for (int r = 0; r < 4; r++) {
          int m = m0 + r;
          float v = acc[si][sj][r] + cb[m];
          long a = (long)b * NB + (long)m * 4096 + n;
          float xv = xres[a];
          out32[a] = fmaf(v, xv, xv);
        }
      }
    }
}

// ---------------- host ----------------
extern "C" void kernel_launch(void* const* d_in, const int* in_sizes, int n_in,
                              void* d_out, int out_size, void* d_ws, size_t ws_size,
                              hipStream_t stream)
{
  const float* x   = (const float*)d_in[0];
  const float* qw  = (const float*)d_in[1];
  const float* qb  = (const float*)d_in[2];
  const float* kw  = (const float*)d_in[3];
  const float* kb  = (const float*)d_in[4];
  const float* vw  = (const float*)d_in[5];
  const float* vb  = (const float*)d_in[6];
  const float* rw  = (const float*)d_in[7];
  const float* rb  = (const float*)d_in[8];
  const float* c1w = (const float*)d_in[9];
  const float* c1b = (const float*)d_in[10];
  const float* c2w = (const float*)d_in[11];
  const float* c2b = (const float*)d_in[12];

  // ws layout (u16 units)
  u16* U     = (u16*)d_ws;
  u16* xT16  = U;                     // 8388608 ; later wvT16
  u16* Qt16  = U + 8388608;           // 8388608 ; later h1T16
  u16* KV16  = U + 16777216;          // 16777216 (K rows 0-255, V rows 256-511 per b)
  u16* wr2   = U + 33554432;          // 589824
  u16* kvT16 = U + 34144256;          // 524288
  float* Fws = (float*)(U + 34668544);
  float* ksum = Fws;                  // 2048
  float* vsum = Fws + 2048;           // 2048
  float* zbuf = Fws + 4096;           // 64 (zero page for conv OOB loads)

  // d_out scratch (all dead before conv2 writes d_out; conv2 reads NOTHING here)
  char* ob = (char*)d_out;
  float* kvpart = (float*)(ob + 0);           // 16777216 B
  float* den    = (float*)(ob + 16777216);    // 131072
  float* rsqK   = (float*)(ob + 16908288);    // 131072
  float* corr   = (float*)(ob + 17039360);    // 4194304  (layout [n][m])
  u16*   w1p16  = (u16*)(ob + 21233664);      // 1179648
  u16*   wr1    = (u16*)(ob + 22413312);      // 1179648
  float* T      = (float*)(ob + 23592960);    // 36864
  u16*   rwT16  = (u16*)(ob + 23629824);      // 131072
  u16*   qw16   = (u16*)(ob + 23760896);      // 131072
  u16*   kvw16  = (u16*)(ob + 23891968);      // 262144
  float* kvbias = (float*)(ob + 24154112);    // 2048
  float* rq     = (float*)(ob + 24158208);    // 131072 (qden output, dead by conv1)
  float* outF   = (float*)d_out;

  u16* wvT16 = xT16;
  u16* h1T16 = Qt16;

  dim3 blk(256);

  // converts(5632) + bias(1) + prep_T(256) + transX(2048)
  prep1<<<7937, blk, 0, stream>>>(qw, kw, vw, rw, c1w, c2w, kb, vb, rb,
                                  qw16, kvw16, rwT16, wr1, wr2, kvbias, zbuf, T,
                                  x, xT16);

  // fused: w1p (36) + Qt (512) + KV (1024) + corr (4096) = 5668 blocks
  gemm3<<<5668, blk, 0, stream>>>(wr1, rwT16, w1p16, xT16, qw16, Qt16,
                                  kvw16, KV16, qb, kvbias, T, c1b, corr);

  sumsqK<<<512, blk, 0, stream>>>(KV16, rsqK);
  scale_sums<<<4096, blk, 0, stream>>>(KV16, rsqK, ksum, vsum);

  gemm_kv<<<dim3(4, 4, 64), blk, 0, stream>>>(KV16, kvpart);
  redkv_qden<<<10240, blk, 0, stream>>>(kvpart, kvT16, Qt16, ksum, rq, den);

  // wvT[b][n][cv] = (Qt @ kvT * rq + vsum) * den
  gemm_wv<<<512, blk, 0, stream>>>(Qt16, kvT16, wvT16, vsum, den, rq);

  conv_gemm<<<256, 512, 0, stream>>>(wvT16, w1p16, corr, nullptr, zbuf,
                                     h1T16, nullptr, 0);
  conv_gemm<<<256, 512, 0, stream>>>(h1T16, wr2, c2b, x, zbuf,
                                     nullptr, outF, 1);
}